// Round 3
// baseline (5132.890 us; speedup 1.0000x reference)
//
#include <hip/hip_runtime.h>
#include <stdint.h>

#define OUTN   200000
#define HID    128
#define NSTEP  64
#define KTOP   50
#define NBINS  1024
#define CAP    4096
#define NBLK   256
#define NTHR   512
#define NWRD   6250     // OUTN/32 bitmask words
#define GRP    8        // barrier groups
#define GSZ    32       // blocks per group
#define SLOTS  64       // candidate slots per block

// ---------- agent-scope (cross-XCD coherent, cache-bypassing) accessors ----------
__device__ __forceinline__ float    gldf(const float* p){ return __hip_atomic_load(p, __ATOMIC_RELAXED, __HIP_MEMORY_SCOPE_AGENT); }
__device__ __forceinline__ void     gstf(float* p, float v){ __hip_atomic_store(p, v, __ATOMIC_RELAXED, __HIP_MEMORY_SCOPE_AGENT); }
__device__ __forceinline__ unsigned gldu(const unsigned* p){ return __hip_atomic_load(p, __ATOMIC_RELAXED, __HIP_MEMORY_SCOPE_AGENT); }
__device__ __forceinline__ void     gstu(unsigned* p, unsigned v){ __hip_atomic_store(p, v, __ATOMIC_RELAXED, __HIP_MEMORY_SCOPE_AGENT); }
__device__ __forceinline__ unsigned long long gld64(const unsigned long long* p){ return __hip_atomic_load(p, __ATOMIC_RELAXED, __HIP_MEMORY_SCOPE_AGENT); }
__device__ __forceinline__ void     gst64(unsigned long long* p, unsigned long long v){ __hip_atomic_store(p, v, __ATOMIC_RELAXED, __HIP_MEMORY_SCOPE_AGENT); }

// dot of one 128-wide f32 row with f32 vector in LDS
__device__ __forceinline__ float dot128f(const float* __restrict__ w, const float* __restrict__ h){
  const float4* w4 = (const float4*)w;
  float acc = 0.f;
  #pragma unroll
  for (int k=0;k<32;k++){
    float4 q = w4[k];
    const float* hp = h + k*4;
    acc += q.x*hp[0] + q.y*hp[1] + q.z*hp[2] + q.w*hp[3];
  }
  return acc;
}

__device__ __forceinline__ int binOf(float l, float rlo, float rsc){
  float b = (l - rlo) * rsc;
  b = fminf(fmaxf(b, 0.f), (float)(NBINS-1));
  return (int)b;
}

// ---------- block reductions (512 threads = 8 waves) ----------
__device__ __forceinline__ void blockRed3(float& mx, float& mn, float& a, int tid, float* sm /*>=24*/){
  __syncthreads();
  #pragma unroll
  for (int o=32;o;o>>=1){
    mx=fmaxf(mx,__shfl_xor(mx,o)); mn=fminf(mn,__shfl_xor(mn,o));
    a+=__shfl_xor(a,o);
  }
  if ((tid&63)==0){ int w=tid>>6; sm[w*3+0]=mx; sm[w*3+1]=mn; sm[w*3+2]=a; }
  __syncthreads();
  if (tid==0){
    for (int k=1;k<8;k++){
      sm[0]=fmaxf(sm[0],sm[k*3+0]); sm[1]=fminf(sm[1],sm[k*3+1]); sm[2]+=sm[k*3+2];
    }
  }
  __syncthreads();
  mx=sm[0]; mn=sm[1]; a=sm[2];
}

__device__ __forceinline__ void blockRedPair(float& p, int& i, int tid, float* smp, int* smi){
  __syncthreads();
  #pragma unroll
  for (int o=32;o;o>>=1){
    float p2=__shfl_xor(p,o); int i2=__shfl_xor(i,o);
    if (p2>p || (p2==p && i2<i)){ p=p2; i=i2; }
  }
  if ((tid&63)==0){ smp[tid>>6]=p; smi[tid>>6]=i; }
  __syncthreads();
  if (tid==0){
    for (int k=1;k<8;k++){
      if (smp[k]>smp[0] || (smp[k]==smp[0] && smi[k]<smi[0])){ smp[0]=smp[k]; smi[0]=smi[k]; }
    }
  }
  __syncthreads();
  p=smp[0]; i=smi[0];
}

__device__ __forceinline__ int blockRedSum(int v, int tid, int* smi){
  __syncthreads();
  #pragma unroll
  for (int o=32;o;o>>=1) v += __shfl_xor(v,o);
  if ((tid&63)==0) smi[tid>>6]=v;
  __syncthreads();
  if (tid==0){ int s=0; for(int k=0;k<8;k++) s+=smi[k]; smi[0]=s; }
  __syncthreads();
  return smi[0];
}

// highest bin bstar with count(bin>=bstar) >= K; if total<K, bstar=0 (take all).
__device__ __forceinline__ void histSelect(unsigned* histL, unsigned* csum, int tid, int K, int* outp){
  int base = NBINS - 2*(tid+1);
  csum[tid] = histL[base] + histL[base+1];
  __syncthreads();
  for (int off=1; off<NTHR; off<<=1){
    unsigned add = (tid>=off) ? csum[tid-off] : 0u;
    __syncthreads();
    csum[tid] += add;
    __syncthreads();
  }
  unsigned pre = (tid==0)?0u:csum[tid-1];
  if (csum[tid] >= (unsigned)K && pre < (unsigned)K){
    unsigned run = pre; int bs = base;
    for (int b=base+1; b>=base; --b){
      run += histL[b];
      if (run >= (unsigned)K){ bs=b; break; }
    }
    outp[0]=bs; outp[1]=(int)run;
  }
  if (tid==NTHR-1 && csum[tid] < (unsigned)K){ outp[0]=0; outp[1]=(int)csum[tid]; }
  __syncthreads();
}

// ---------- tree grid barrier (fence-free; all shared RW data is agent-scope) ----------
// 8 arrival counters (one 256B line each) + 1 global counter + 8 release lines.
// Monotonic; s = barrier sequence number (1-based).
__device__ __forceinline__ void gsync(unsigned* garr, unsigned* gctr, unsigned* grel,
                                      int bid, unsigned s){
  asm volatile("s_waitcnt vmcnt(0) lgkmcnt(0)" ::: "memory");
  __syncthreads();
  if (threadIdx.x==0){
    int g = bid>>5;                       // 32 blocks per group
    unsigned r = __hip_atomic_fetch_add(garr+g*64, 1u, __ATOMIC_RELAXED, __HIP_MEMORY_SCOPE_AGENT);
    if (r == s*GSZ-1u){                   // last arriver in group this round
      unsigned q = __hip_atomic_fetch_add(gctr, 1u, __ATOMIC_RELAXED, __HIP_MEMORY_SCOPE_AGENT);
      if (q == s*GRP-1u){                 // last group: release everyone
        #pragma unroll
        for (int k=0;k<GRP;k++)
          __hip_atomic_store(grel+k*64, s, __ATOMIC_RELAXED, __HIP_MEMORY_SCOPE_AGENT);
      }
    }
    while (__hip_atomic_load(grel+g*64, __ATOMIC_RELAXED, __HIP_MEMORY_SCOPE_AGENT) < s)
      __builtin_amdgcn_s_sleep(2);
  }
  __syncthreads();
  asm volatile("" ::: "memory");
}

// ---------- init kernel ----------
extern "C" __global__ void k_init(const int* __restrict__ x,
                                  const float* __restrict__ b_ih, const float* __restrict__ b_hh,
                                  unsigned* mask_bits, unsigned* inx_bits,
                                  float* pubInv, float* h_ws, float* c_ws,
                                  unsigned* garr, unsigned* gctr, unsigned* grel)
{
  int tid = threadIdx.x;  // single block, 1024 threads
  for (int i=tid;i<NWRD;i+=1024){ mask_bits[i]=0xFFFFFFFFu; inx_bits[i]=0u; }
  for (int i=tid;i<GRP*64;i+=1024){ garr[i]=0u; grel[i]=0u; }
  if (tid<64) gctr[tid]=0u;
  if (tid==0) pubInv[0]=0.f;
  if (tid<HID){
    // state after reference step 0 (emb=0, h=c=0)
    float ig=b_ih[tid]       +b_hh[tid];
    float gg=b_ih[tid+2*HID] +b_hh[tid+2*HID];
    float og=b_ih[tid+3*HID] +b_hh[tid+3*HID];
    float si=1.f/(1.f+expf(-ig)), so=1.f/(1.f+expf(-og));
    float cn=si*tanhf(gg);
    c_ws[tid]=cn; h_ws[tid]=so*tanhf(cn);
  }
  __syncthreads();
  if (tid<200){
    int v = x[tid]-1;                       // 1-indexed items
    if (v>=0 && v<OUTN) atomicOr(&inx_bits[v>>5], 1u<<(v&31));
  }
}

// ---------- fused persistent kernel ----------
struct FusedP {
  const float* emb;  const float* Wih;  const float* Whh;
  const float* bih;  const float* bhh;  const float* Wout; const float* bout;
  float* out;
  float* l_ws; float* partials;
  unsigned* mask_bits; unsigned* inx_bits;
  unsigned* cntb; unsigned long long* cand;
  float* pubInv; float* h_ws; float* c_ws;
  unsigned* garr; unsigned* gctr; unsigned* grel;
};

extern "C" __global__ void __launch_bounds__(NTHR) k_fused(FusedP p)
{
  __shared__ float    h_l[HID];
  __shared__ float    emb_l[HID];
  __shared__ float    gates[4*HID];
  __shared__ float    c_l[HID];
  __shared__ unsigned m_l[32];
  __shared__ unsigned hl[NBINS];
  __shared__ unsigned csum[NTHR];
  __shared__ unsigned cnt_l[NBLK];
  __shared__ float    smf[24];
  __shared__ float    smp[8];
  __shared__ int      smi[8];
  __shared__ int      s_sel[2];
  __shared__ int      s_nc, s_cnt, s_flag;

  const int tid=threadIdx.x, bid=blockIdx.x;
  // balanced contiguous chunks: blocks 0..63 take 782 rows, rest 781
  const int start = bid*781 + (bid<64 ? bid : 64);
  const int cnt   = 781 + (bid<64 ? 1 : 0);
  const int w_lo  = start>>5;
  const int nw    = ((start+cnt-1)>>5) - w_lo + 1;   // <= 26
  unsigned bs = 0;

  // block 0 keeps c in LDS for the whole kernel (only it touches c)
  if (bid==0 && tid<HID) c_l[tid]=gldf(&p.c_ws[tid]);

  // register-carried (logit, mask) for this thread's 2 rows, step t -> t+1
  float lv0=0.f, lv1=0.f; unsigned mv0=0u, mv1=0u;

  for (int t=0; t<NSTEP; ++t){
    // ================= phase A: emit prev probs + logits + stats + local top-K =================
    if (tid<HID) h_l[tid]=gldf(&p.h_ws[tid]);
    if (tid<nw)  m_l[tid]=gldu(&p.mask_bits[w_lo+tid]);
    for (int i=tid;i<NBINS;i+=NTHR) hl[i]=0u;
    const float invSp = gldf(p.pubInv);
    __syncthreads();

    float mx=-3e38f, mn=3e38f, se=0.f;
    float* orowp = p.out + 2*NSTEP + (size_t)(t-1)*OUTN;   // valid only if t>0
    {
      int j=tid;
      if (j<cnt){
        int row=start+j;
        if (t>0) __builtin_nontemporal_store(mv0 ? expf(lv0)*invSp : 0.f, &orowp[row]);
        float l = dot128f(p.Wout+(size_t)row*HID, h_l) + p.bout[row];
        gstf(&p.l_ws[row], l);
        lv0=l; se += expf(l)-1.f;
        mv0 = (m_l[(row>>5)-w_lo]>>(row&31))&1u;
        if (mv0){ mx=fmaxf(mx,l); mn=fminf(mn,l); }
      } else { mv0=0u; }
      j=tid+NTHR;
      if (j<cnt){
        int row=start+j;
        if (t>0) __builtin_nontemporal_store(mv1 ? expf(lv1)*invSp : 0.f, &orowp[row]);
        float l = dot128f(p.Wout+(size_t)row*HID, h_l) + p.bout[row];
        gstf(&p.l_ws[row], l);
        lv1=l; se += expf(l)-1.f;
        mv1 = (m_l[(row>>5)-w_lo]>>(row&31))&1u;
        if (mv1){ mx=fmaxf(mx,l); mn=fminf(mn,l); }
      } else { mv1=0u; }
    }
    blockRed3(mx,mn,se,tid,smf);
    if (tid==0){ float* q=&p.partials[bid*4]; gstf(q,mx); gstf(q+1,mn); gstf(q+2,se); }

    // local top-K candidates via per-block histogram over [mn, mx]
    const bool okloc = (mx>mn);    // block-uniform (reduced values)
    if (okloc){
      const float rsc=(float)NBINS/(mx-mn);
      if (mv0) atomicAdd(&hl[binOf(lv0,mn,rsc)],1u);
      if (mv1) atomicAdd(&hl[binOf(lv1,mn,rsc)],1u);
      if (tid==0){ s_cnt=0; s_sel[0]=NBINS; s_sel[1]=0; }
      __syncthreads();
      histSelect(hl,csum,tid,KTOP,s_sel);
      const int bstar=s_sel[0];
      if (mv0 && binOf(lv0,mn,rsc)>=bstar){
        int pos=atomicAdd(&s_cnt,1);
        if (pos<SLOTS){
          int row=start+tid;
          gst64(&p.cand[bid*SLOTS+pos],
                ((unsigned long long)__float_as_uint(lv0)<<32)|(unsigned)row);
        }
      }
      if (mv1 && binOf(lv1,mn,rsc)>=bstar){
        int pos=atomicAdd(&s_cnt,1);
        if (pos<SLOTS){
          int row=start+tid+NTHR;
          gst64(&p.cand[bid*SLOTS+pos],
                ((unsigned long long)__float_as_uint(lv1)<<32)|(unsigned)row);
        }
      }
      __syncthreads();
      if (tid==0) gstu(&p.cntb[bid],(unsigned)s_cnt);
    } else {
      if (tid==0) gstu(&p.cntb[bid],0x7fffffffu);   // overflow marker -> global fallback
    }
    ++bs; gsync(p.garr,p.gctr,p.grel,bid,bs);

    // ================= phase B: block 0 selects + LSTM; others wait =================
    if (bid==0){
      float gmx=-3e38f,gmn=3e38f,gse=0.f;
      if (tid<NBLK){
        const float* q=&p.partials[tid*4];
        gmx=gldf(q); gmn=gldf(q+1); gse=gldf(q+2);
        cnt_l[tid]=gldu(&p.cntb[tid]);
      }
      blockRed3(gmx,gmn,gse,tid,smf);
      const float invS = 1.f/(2.0e5f+gse);
      if (tid==0) s_flag=0;
      __syncthreads();
      if (tid<NBLK && cnt_l[tid]>SLOTS) s_flag=1;
      __syncthreads();
      int a, fb;
      if (!s_flag){
        // ---- fast merge: union of per-block top-K lists, held in registers ----
        unsigned long long sv[32]; unsigned um=0u;
        #pragma unroll
        for (int k=0;k<32;k++){
          int j=tid+k*NTHR; int b=j>>6, s=j&63;
          if (s < (int)cnt_l[b]){ sv[k]=gld64(&p.cand[j]); um|=1u<<k; }
          else sv[k]=0ull;
        }
        float bp=-3.4e38f; int bi=0x7fffffff;
        float hp=-3.4e38f; int hidx=0x7fffffff;
        #pragma unroll
        for (int k=0;k<32;k++){
          if ((um>>k)&1u){
            int idx=(int)(unsigned)(sv[k]&0xffffffffu);
            float l=__uint_as_float((unsigned)(sv[k]>>32));
            if (l>bp || (l==bp && idx<bi)){ bp=l; bi=idx; }
            if (((p.inx_bits[idx>>5]>>(idx&31))&1u) && (l>hp || (l==hp && idx<hidx))){ hp=l; hidx=idx; }
          }
        }
        blockRedPair(bp,bi,tid,smp,smi);
        blockRedPair(hp,hidx,tid,smp,smi);
        if (hidx != 0x7fffffff){
          int better=0;
          #pragma unroll
          for (int k=0;k<32;k++){
            if ((um>>k)&1u){
              int idx=(int)(unsigned)(sv[k]&0xffffffffu);
              float l=__uint_as_float((unsigned)(sv[k]>>32));
              better += (l>hp || (l==hp && idx<hidx)) ? 1 : 0;
            }
          }
          better=blockRedSum(better,tid,smi);
          if (better<KTOP){ a=hidx; fb=1; } else { a=bi; fb=-1; }
        } else { a=bi; fb=-1; }
      } else {
        // ---- exact fallback (degenerate / overflow) ----
        unsigned* candf=(unsigned*)p.cand;
        int nc;
        if (gmn>=gmx){
          // all masked logits tied: first KTOP masked rows, fully parallel.
          // First 512 words = 16384 bits, >=16320 set (<=64 cleared) -> always enough.
          unsigned w=gldu(&p.mask_bits[tid]);
          hl[tid]=w; csum[tid]=(unsigned)__popc(w);
          __syncthreads();
          for (int off=1; off<NTHR; off<<=1){
            unsigned add=(tid>=off)?csum[tid-off]:0u;
            __syncthreads();
            csum[tid]+=add;
            __syncthreads();
          }
          unsigned pre = tid? csum[tid-1]:0u;
          if (pre<(unsigned)KTOP){
            unsigned word=hl[tid]; unsigned r=pre;
            for (int b2=0;b2<32 && r<(unsigned)KTOP;b2++){
              if ((word>>b2)&1u){ gstu(&candf[r],(unsigned)(tid*32+b2)); r++; }
            }
          }
          __syncthreads();
          nc = (int)(csum[NTHR-1]<(unsigned)KTOP ? csum[NTHR-1] : (unsigned)KTOP);
        } else {
          // exact histogram over [gmn,gmx] on l_ws
          for (int i=tid;i<NBINS;i+=NTHR) hl[i]=0u;
          if (tid==0){ s_sel[0]=NBINS; s_sel[1]=0; }
          __syncthreads();
          const float sc2=(float)NBINS/(gmx-gmn);
          for (int i=tid;i<OUTN;i+=NTHR)
            if ((gldu(&p.mask_bits[i>>5])>>(i&31))&1u)
              atomicAdd(&hl[binOf(gldf(&p.l_ws[i]),gmn,sc2)],1u);
          __syncthreads();
          histSelect(hl,csum,tid,KTOP,s_sel);
          int b2=s_sel[0], c2=s_sel[1];
          if (c2<=CAP){
            if (tid==0) s_cnt=0;
            __syncthreads();
            for (int i=tid;i<OUTN;i+=NTHR){
              if ((gldu(&p.mask_bits[i>>5])>>(i&31))&1u && binOf(gldf(&p.l_ws[i]),gmn,sc2)>=b2){
                int q=atomicAdd(&s_cnt,1);
                if (q<CAP) gstu(&candf[q],(unsigned)i);
              }
            }
            __syncthreads();
            nc = (s_cnt<CAP ? s_cnt : CAP);
          } else {
            if (tid==0){
              int c=0;
              for (int i=0;i<OUTN && c<KTOP;i++)
                if (((gldu(&p.mask_bits[i>>5])>>(i&31))&1u) && binOf(gldf(&p.l_ws[i]),gmn,sc2)>=b2)
                  gstu(&candf[c++],(unsigned)i);
              s_nc=c;
            }
            __syncthreads();
            nc=s_nc;
          }
        }
        // selection over candf (ordered by l desc, idx asc)
        float bp=-3.4e38f; int bi=0x7fffffff;
        float hp=-3.4e38f; int hidx=0x7fffffff;
        for (int j=tid;j<nc;j+=NTHR){
          int idx=(int)gldu(&candf[j]);
          float l=gldf(&p.l_ws[idx]);
          if (l>bp || (l==bp && idx<bi)){ bp=l; bi=idx; }
          if (((p.inx_bits[idx>>5]>>(idx&31))&1u) && (l>hp || (l==hp && idx<hidx))){ hp=l; hidx=idx; }
        }
        blockRedPair(bp,bi,tid,smp,smi);
        blockRedPair(hp,hidx,tid,smp,smi);
        if (hidx != 0x7fffffff){
          int better=0;
          for (int j=tid;j<nc;j+=NTHR){
            int idx=(int)gldu(&candf[j]);
            float l=gldf(&p.l_ws[idx]);
            better += (l>hp || (l==hp && idx<hidx)) ? 1 : 0;
          }
          better=blockRedSum(better,tid,smi);
          if (better<KTOP){ a=hidx; fb=1; } else { a=bi; fb=-1; }
        } else { a=bi; fb=-1; }
      }
      if (a<0 || a>=OUTN) a=0;   // safety clamp

      if (tid==0){
        p.out[t]       = (float)a;
        p.out[NSTEP+t] = (float)fb;
        atomicAnd(&p.mask_bits[a>>5], ~(1u<<(a&31)));
        gstf(p.pubInv, invS);
      }
      // LSTM update (h_l still holds this step's h from phase A)
      if (tid<HID) emb_l[tid]=p.emb[(size_t)a*HID+tid]*(float)fb;
      __syncthreads();
      float g = dot128f(p.Wih+(size_t)tid*HID, emb_l) + dot128f(p.Whh+(size_t)tid*HID, h_l)
              + p.bih[tid] + p.bhh[tid];
      gates[tid]=g;
      __syncthreads();
      if (tid<HID){
        float ig=gates[tid], fg=gates[tid+HID], gg=gates[tid+2*HID], og=gates[tid+3*HID];
        float si=1.f/(1.f+expf(-ig)), sf=1.f/(1.f+expf(-fg)), so=1.f/(1.f+expf(-og));
        float cn=sf*c_l[tid]+si*tanhf(gg);
        float hn=so*tanhf(cn);
        c_l[tid]=cn; gstf(&p.h_ws[tid],hn);
      }
    }
    ++bs; gsync(p.garr,p.gctr,p.grel,bid,bs);
  }

  // epilogue: emit probs for the last step from carried registers
  {
    const float invSL = gldf(p.pubInv);
    float* orow = p.out + 2*NSTEP + (size_t)(NSTEP-1)*OUTN;
    int j=tid;
    if (j<cnt){ int row=start+j; __builtin_nontemporal_store(mv0 ? expf(lv0)*invSL : 0.f, &orow[row]); }
    j=tid+NTHR;
    if (j<cnt){ int row=start+j; __builtin_nontemporal_store(mv1 ? expf(lv1)*invSL : 0.f, &orow[row]); }
  }
}

// ---------- host ----------
extern "C" void kernel_launch(void* const* d_in, const int* in_sizes, int n_in,
                              void* d_out, int out_size, void* d_ws, size_t ws_size,
                              hipStream_t stream)
{
  const int*   x    = (const int*)d_in[0];
  const float* emb  = (const float*)d_in[1];
  const float* Wih  = (const float*)d_in[2];
  const float* Whh  = (const float*)d_in[3];
  const float* bih  = (const float*)d_in[4];
  const float* bhh  = (const float*)d_in[5];
  const float* Wout = (const float*)d_in[6];
  const float* bout = (const float*)d_in[7];
  float* out = (float*)d_out;

  char* ws = (char*)d_ws;
  float*    l_ws      = (float*)(ws + 0);          // 800000 B (pad 800256)
  float*    partials  = (float*)(ws + 800256);     // 256*16 = 4096
  unsigned* mask_bits = (unsigned*)(ws + 804352);  // 25000 (+pad)
  unsigned* inx_bits  = (unsigned*)(ws + 829440);  // 25000 (+pad)
  unsigned* cntb      = (unsigned*)(ws + 854528);  // 1024
  unsigned long long* cand = (unsigned long long*)(ws + 855552); // 256*64*8 = 131072
  unsigned* garr      = (unsigned*)(ws + 986624);  // 8 lines * 256B = 2048
  unsigned* gctr      = (unsigned*)(ws + 988672);  // 256
  unsigned* grel      = (unsigned*)(ws + 988928);  // 2048
  float*    pubInv    = (float*)(ws + 990976);     // 256
  float*    h_ws      = (float*)(ws + 991232);     // 512
  float*    c_ws      = (float*)(ws + 991744);     // 512 -> total 992256 B

  hipLaunchKernelGGL(k_init, dim3(1), dim3(1024), 0, stream,
                     x, bih, bhh, mask_bits, inx_bits, pubInv, h_ws, c_ws, garr, gctr, grel);

  FusedP p;
  p.emb=emb; p.Wih=Wih; p.Whh=Whh; p.bih=bih; p.bhh=bhh; p.Wout=Wout; p.bout=bout;
  p.out=out; p.l_ws=l_ws; p.partials=partials;
  p.mask_bits=mask_bits; p.inx_bits=inx_bits;
  p.cntb=cntb; p.cand=cand;
  p.pubInv=pubInv; p.h_ws=h_ws; p.c_ws=c_ws;
  p.garr=garr; p.gctr=gctr; p.grel=grel;

  void* args[] = { &p };
  hipLaunchCooperativeKernel((const void*)k_fused, dim3(NBLK), dim3(NTHR), args, 0, stream);
}